// Round 12
// baseline (146.452 us; speedup 1.0000x reference)
//
#include <hip/hip_runtime.h>

#define N_NODES 10000
#define N_EDGES 160000
#define D_EDGE  64
#define C_CH    16
#define HW      64            // H*W = 8*8
#define HID     128
#define NODE_ELEMS 1024          // C*H*W floats per node
#define NSEG    (2 * N_NODES)    // (node,dir): dir 0=out(r<c), 1=in(r>c)
#define CAP     64               // bucket capacity per segment
#define MLPB    (N_EDGES / 64)   // 2500 GEMM blocks
#define CASTB   2500             // cast blocks appended to same grid

typedef __attribute__((ext_vector_type(8))) short short8;   // 8 bf16 (4 VGPR)
typedef __attribute__((ext_vector_type(4))) float f32x4;

__device__ __forceinline__ unsigned bf16_rne(float f) {
    unsigned u = __float_as_uint(f);
    return (u + 0x7FFFu + ((u >> 16) & 1u)) >> 16;
}
__device__ __forceinline__ unsigned pk2(float a, float b) {
    return bf16_rne(a) | (bf16_rne(b) << 16);
}
__device__ __forceinline__ float ubf(unsigned u, int hi) {
    return __uint_as_float(hi ? (u & 0xFFFF0000u) : (u << 16));
}
__device__ __forceinline__ short8 pack_bf16x8(float4 lo, float4 hi) {
    union { unsigned u[4]; short8 s; } r;
    r.u[0] = pk2(lo.x, lo.y); r.u[1] = pk2(lo.z, lo.w);
    r.u[2] = pk2(hi.x, hi.y); r.u[3] = pk2(hi.z, hi.w);
    return r.s;
}

// ---- K0: prep — W1 (fp32 [k][n]) -> bf16 transposed [n][k] ----
__global__ __launch_bounds__(256) void k_prep(
    const float* __restrict__ W1, unsigned short* __restrict__ W1bfT)
{
    int tid = threadIdx.x;
    int s0 = tid * 32;                 // 8192 shorts / 256 threads
    int n  = s0 >> 6;
    #pragma unroll
    for (int i = 0; i < 32; ++i) {
        int s = s0 + i;
        int k = s & 63;
        W1bfT[s] = (unsigned short)bf16_rne(W1[k * HID + n]);
    }
}

// ---- K1: LDS-free MFMA edge-MLP + exp + bucket scatter, plus x->bf16 cast ----
__global__ __launch_bounds__(256) void k_mlpcast(
    const float* __restrict__ ea, const unsigned short* __restrict__ W1bfT,
    const float* __restrict__ b1, const float* __restrict__ W2,
    const float* __restrict__ b2,
    const int* __restrict__ row, const int* __restrict__ col,
    const float* __restrict__ x, unsigned* __restrict__ xb,
    float* __restrict__ dec, float* __restrict__ s_sum,
    int* __restrict__ cursor, int2* __restrict__ bucket)
{
    const int tid = threadIdx.x;

    if (blockIdx.x >= MLPB) {
        // ---- cast path: x fp32 -> packed bf16 (RNE), 2 uint4 per thread ----
        int t = (blockIdx.x - MLPB) * 256 + tid;
        #pragma unroll
        for (int h = 0; h < 2; ++h) {
            int idx = t + h * (CASTB * 256);
            float4 a = ((const float4*)x)[idx * 2];
            float4 b = ((const float4*)x)[idx * 2 + 1];
            uint4 o;
            o.x = pk2(a.x, a.y); o.y = pk2(a.z, a.w);
            o.z = pk2(b.x, b.y); o.w = pk2(b.z, b.w);
            ((uint4*)xb)[idx] = o;
        }
        return;
    }

    // ---- MFMA MLP: 64 edges x 128 hidden, K=64; A & B direct from global ----
    __shared__ float s_w2[HID], s_b1[HID];
    __shared__ float s_logit[64];

    const int eb = blockIdx.x * 64;
    if (tid < HID) { s_w2[tid] = W2[tid]; s_b1[tid] = b1[tid]; }

    const int lane = tid & 63, w = tid >> 6;
    const int i15 = lane & 15, g = lane >> 4;
    const int m = w * 16 + i15;            // edge row within 64-edge tile

    // B fragments (W1^T, identical for all blocks -> L2-broadcast): 64 VGPR
    short8 bfrag[2][8];
    #pragma unroll
    for (int kt = 0; kt < 2; ++kt)
        #pragma unroll
        for (int t = 0; t < 8; ++t)
            bfrag[kt][t] = *(const short8*)&W1bfT[(t * 16 + i15) * 64 + kt * 32 + g * 8];

    // A fragments: per-lane fp32 load + convert (each (edge,k) hits one lane)
    short8 afrag[2];
    #pragma unroll
    for (int kt = 0; kt < 2; ++kt) {
        const float4* src = (const float4*)&ea[(size_t)(eb + m) * D_EDGE + kt * 32 + g * 8];
        afrag[kt] = pack_bf16x8(src[0], src[1]);
    }

    f32x4 acc[8];
    #pragma unroll
    for (int t = 0; t < 8; ++t) acc[t] = (f32x4){0.f, 0.f, 0.f, 0.f};
    #pragma unroll
    for (int kt = 0; kt < 2; ++kt)
        #pragma unroll
        for (int t = 0; t < 8; ++t)
            acc[t] = __builtin_amdgcn_mfma_f32_16x16x32_bf16(afrag[kt], bfrag[kt][t],
                                                             acc[t], 0, 0, 0);
    __syncthreads();   // s_w2/s_b1 ready (overlapped with MFMA)

    // logit[m] = sum_n relu(h[m][n]+b1[n]) * W2[n];  m = w*16 + g*4 + r
    float loc[4] = {0.f, 0.f, 0.f, 0.f};
    #pragma unroll
    for (int t = 0; t < 8; ++t) {
        float w2v = s_w2[t * 16 + i15];
        float bv  = s_b1[t * 16 + i15];
        #pragma unroll
        for (int r = 0; r < 4; ++r)
            loc[r] = fmaf(fmaxf(acc[t][r] + bv, 0.f), w2v, loc[r]);
    }
    #pragma unroll
    for (int r = 0; r < 4; ++r) {
        #pragma unroll
        for (int off = 1; off < 16; off <<= 1)
            loc[r] += __shfl_xor(loc[r], off);
    }
    if (i15 == 0) {
        #pragma unroll
        for (int r = 0; r < 4; ++r)
            s_logit[w * 16 + g * 4 + r] = loc[r];
    }
    __syncthreads();

    if (tid < 64) {
        int e = eb + tid;
        float logit = s_logit[tid] + b2[0];
        dec[e] = logit;
        int r = row[e], c = col[e];
        if (r != c) {
            float ex = expf(logit);          // logits ~ +-3, no max-shift needed
            int seg = 2 * r + ((r < c) ? 0 : 1);
            atomicAdd(&s_sum[seg], ex);
            int pos = atomicAdd(&cursor[seg], 1);
            if (pos < CAP)                   // P(overflow) ~ e^-30
                bucket[((size_t)seg << 6) + pos] = make_int2(c, __float_as_int(ex));
        }
    }
}

// ---- K2: wave-per-node gather (16 loads in flight) + fused 1x1 conv ----
__device__ __forceinline__ void fma8(float4& lo, float4& hi, uint4 v, float w) {
    lo.x = fmaf(w, __uint_as_float(v.x << 16),          lo.x);
    lo.y = fmaf(w, __uint_as_float(v.x & 0xFFFF0000u),  lo.y);
    lo.z = fmaf(w, __uint_as_float(v.y << 16),          lo.z);
    lo.w = fmaf(w, __uint_as_float(v.y & 0xFFFF0000u),  lo.w);
    hi.x = fmaf(w, __uint_as_float(v.z << 16),          hi.x);
    hi.y = fmaf(w, __uint_as_float(v.z & 0xFFFF0000u),  hi.y);
    hi.z = fmaf(w, __uint_as_float(v.w << 16),          hi.z);
    hi.w = fmaf(w, __uint_as_float(v.w & 0xFFFF0000u),  hi.w);
}

__device__ __forceinline__ void gbatch8(const uint4* __restrict__ xbn,
    const int2* ecw, float4& A0, float4& A1, float4& A2, float4& A3)
{
    uint4 v0[8], v1[8];
    #pragma unroll
    for (int j = 0; j < 8; ++j) {
        size_t base = (size_t)ecw[j].x * 128;
        v0[j] = xbn[base]; v1[j] = xbn[base + 64];
    }
    #pragma unroll
    for (int j = 0; j < 8; ++j) {
        float w = __int_as_float(ecw[j].y);
        fma8(A0, A1, v0[j], w); fma8(A2, A3, v1[j], w);
    }
}
__device__ __forceinline__ void gbatch4(const uint4* __restrict__ xbn,
    const int2* ecw, float4& A0, float4& A1, float4& A2, float4& A3)
{
    uint4 v0[4], v1[4];
    #pragma unroll
    for (int j = 0; j < 4; ++j) {
        size_t base = (size_t)ecw[j].x * 128;
        v0[j] = xbn[base]; v1[j] = xbn[base + 64];
    }
    #pragma unroll
    for (int j = 0; j < 4; ++j) {
        float w = __int_as_float(ecw[j].y);
        fma8(A0, A1, v0[j], w); fma8(A2, A3, v1[j], w);
    }
}

__global__ __launch_bounds__(256, 4) void k_gather(
    const uint4* __restrict__ xb,
    const float* __restrict__ s_sum, const int* __restrict__ cursor,
    const int2* __restrict__ bucket,
    const float* __restrict__ Wn, const float* __restrict__ bn,
    float* __restrict__ out)
{
    const int wv = threadIdx.x >> 6;        // wave -> node
    const int ln = threadIdx.x & 63;
    const int n  = blockIdx.x * 4 + wv;

    __shared__ unsigned sflow[4][2][512];   // packed bf16 [node][dir] 16KB
    __shared__ unsigned sxp[4][512];        // packed bf16 self-x      8KB
    __shared__ float    sW[C_CH * 3 * C_CH];
    __shared__ float    sbn[C_CH];
    __shared__ int2     s_ecw[4][128];      // dir0 @0..63, dir1 @64..127

    for (int i = threadIdx.x; i < C_CH * 3 * C_CH; i += 256) sW[i] = Wn[i];
    if (threadIdx.x < C_CH) sbn[threadIdx.x] = bn[threadIdx.x];

    ((uint4*)sxp[wv])[ln]      = xb[(size_t)n * 128 + ln];
    ((uint4*)sxp[wv])[ln + 64] = xb[(size_t)n * 128 + 64 + ln];

    const int seg0 = 2 * n, seg1 = 2 * n + 1;
    const int c0 = min(cursor[seg0], CAP);
    const int c1 = min(cursor[seg1], CAP);
    if (ln < c0) s_ecw[wv][ln]      = bucket[((size_t)seg0 << 6) + ln];
    if (ln < c1) s_ecw[wv][64 + ln] = bucket[((size_t)seg1 << 6) + ln];
    // wave-private LDS slices: no barrier needed before use

    float4 a0 = make_float4(0,0,0,0), a1 = make_float4(0,0,0,0);
    float4 a2 = make_float4(0,0,0,0), a3 = make_float4(0,0,0,0);
    float4 b0 = make_float4(0,0,0,0), b1 = make_float4(0,0,0,0);
    float4 b2 = make_float4(0,0,0,0), b3 = make_float4(0,0,0,0);
    const uint4* xbn = xb + ln;

    int i = 0;
    for (; i + 8 <= c0; i += 8) gbatch8(xbn, &s_ecw[wv][i], a0, a1, a2, a3);
    for (; i + 4 <= c0; i += 4) gbatch4(xbn, &s_ecw[wv][i], a0, a1, a2, a3);
    for (; i < c0; ++i) {
        int2 e = s_ecw[wv][i];
        size_t base = (size_t)e.x * 128;
        float w = __int_as_float(e.y);
        fma8(a0, a1, xbn[base], w); fma8(a2, a3, xbn[base + 64], w);
    }
    i = 0;
    for (; i + 8 <= c1; i += 8) gbatch8(xbn, &s_ecw[wv][64 + i], b0, b1, b2, b3);
    for (; i + 4 <= c1; i += 4) gbatch4(xbn, &s_ecw[wv][64 + i], b0, b1, b2, b3);
    for (; i < c1; ++i) {
        int2 e = s_ecw[wv][64 + i];
        size_t base = (size_t)e.x * 128;
        float w = __int_as_float(e.y);
        fma8(b0, b1, xbn[base], w); fma8(b2, b3, xbn[base + 64], w);
    }

    const float r0 = 1.0f / fmaxf(s_sum[seg0], 1e-30f);
    const float r1 = 1.0f / fmaxf(s_sum[seg1], 1e-30f);

    unsigned* f0 = sflow[wv][0];   // dir0 = flow_out
    unsigned* f1 = sflow[wv][1];   // dir1 = flow_in
    f0[ln * 4 + 0]       = pk2(a0.x * r0, a0.y * r0);
    f0[ln * 4 + 1]       = pk2(a0.z * r0, a0.w * r0);
    f0[ln * 4 + 2]       = pk2(a1.x * r0, a1.y * r0);
    f0[ln * 4 + 3]       = pk2(a1.z * r0, a1.w * r0);
    f0[256 + ln * 4 + 0] = pk2(a2.x * r0, a2.y * r0);
    f0[256 + ln * 4 + 1] = pk2(a2.z * r0, a2.w * r0);
    f0[256 + ln * 4 + 2] = pk2(a3.x * r0, a3.y * r0);
    f0[256 + ln * 4 + 3] = pk2(a3.z * r0, a3.w * r0);
    f1[ln * 4 + 0]       = pk2(b0.x * r1, b0.y * r1);
    f1[ln * 4 + 1]       = pk2(b0.z * r1, b0.w * r1);
    f1[ln * 4 + 2]       = pk2(b1.x * r1, b1.y * r1);
    f1[ln * 4 + 3]       = pk2(b1.z * r1, b1.w * r1);
    f1[256 + ln * 4 + 0] = pk2(b2.x * r1, b2.y * r1);
    f1[256 + ln * 4 + 1] = pk2(b2.z * r1, b2.w * r1);
    f1[256 + ln * 4 + 2] = pk2(b3.x * r1, b3.y * r1);
    f1[256 + ln * 4 + 3] = pk2(b3.z * r1, b3.w * r1);

    __syncthreads();   // sW/sbn ready (flow/x slices are wave-private)

    // epilogue: thread -> (node wv, hw=ln), all 16 output channels
    const int hw = ln;
    const int hv = hw & 1, hq = hw >> 1;
    float vx[C_CH], vi[C_CH], vo[C_CH];
    #pragma unroll
    for (int c = 0; c < C_CH; ++c) {
        vx[c] = ubf(sxp[wv][c * 32 + hq],      hv);
        vo[c] = ubf(sflow[wv][0][c * 32 + hq], hv);
        vi[c] = ubf(sflow[wv][1][c * 32 + hq], hv);
    }
    float* outb = out + (size_t)n * NODE_ELEMS;
    #pragma unroll
    for (int o = 0; o < C_CH; ++o) {
        float a = sbn[o];
        const float* wr = &sW[o * 3 * C_CH];
        #pragma unroll
        for (int c = 0; c < C_CH; ++c) {
            a = fmaf(vx[c], wr[c],            a);
            a = fmaf(vi[c], wr[C_CH + c],     a);
            a = fmaf(vo[c], wr[2 * C_CH + c], a);
        }
        outb[o * HW + hw] = a;
    }
}

extern "C" void kernel_launch(void* const* d_in, const int* in_sizes, int n_in,
                              void* d_out, int out_size, void* d_ws, size_t ws_size,
                              hipStream_t stream)
{
    const float* x         = (const float*)d_in[0];
    const float* edge_attr = (const float*)d_in[1];
    const float* W1        = (const float*)d_in[2];
    const float* b1        = (const float*)d_in[3];
    const float* W2        = (const float*)d_in[4];
    const float* b2        = (const float*)d_in[5];
    const float* Wn        = (const float*)d_in[6];
    const float* bn        = (const float*)d_in[7];
    const int*   eidx      = (const int*)d_in[8];
    const int*   row       = eidx;
    const int*   col       = eidx + N_EDGES;

    float* out = (float*)d_out;                          // [N,16,8,8]
    float* dec = out + (size_t)N_NODES * NODE_ELEMS;     // [E,1] logits

    // ws layout (4B units):
    // xb16[N*512 uints] | bucket[NSEG*CAP int2] | s_sum[NSEG] | cursor[NSEG] | W1bfT
    unsigned* xb16   = (unsigned*)d_ws;                                   // 20.48 MB
    int2*     bucket = (int2*)(xb16 + (size_t)N_NODES * NODE_ELEMS / 2);  // 10.24 MB
    float*    s_sum  = (float*)(bucket + (size_t)NSEG * CAP);
    int*      cursor = (int*)(s_sum + NSEG);
    unsigned short* W1bfT = (unsigned short*)(cursor + NSEG);             // 16 KB

    hipMemsetAsync(s_sum, 0, 2 * (size_t)NSEG * sizeof(int), stream);

    k_prep<<<1, 256, 0, stream>>>(W1, W1bfT);
    k_mlpcast<<<MLPB + CASTB, 256, 0, stream>>>(edge_attr, W1bfT, b1, W2, b2,
                                                row, col, x, xb16,
                                                dec, s_sum, cursor, bucket);
    k_gather<<<N_NODES / 4, 256, 0, stream>>>((const uint4*)xb16, s_sum, cursor,
                                              bucket, Wn, bn, out);
}

// Round 13
// 98.203 us; speedup vs baseline: 1.4913x; 1.4913x over previous
//
#include <hip/hip_runtime.h>

#define N_NODES 10000
#define N_EDGES 160000
#define D_EDGE  64
#define C_CH    16
#define HW      64            // H*W = 8*8
#define HID     128
#define NODE_ELEMS 1024          // C*H*W floats per node
#define NSEG    (2 * N_NODES)    // (node,dir): dir 0=out(r<c), 1=in(r>c)
#define CAP     64               // bucket capacity per segment
#define MLPB    (N_EDGES / 64)   // 2500 GEMM blocks
#define CASTB   2500             // cast blocks appended to same grid

typedef __attribute__((ext_vector_type(8))) short short8;   // 8 bf16 (4 VGPR)
typedef __attribute__((ext_vector_type(4))) float f32x4;

__device__ __forceinline__ unsigned bf16_rne(float f) {
    unsigned u = __float_as_uint(f);
    return (u + 0x7FFFu + ((u >> 16) & 1u)) >> 16;
}
__device__ __forceinline__ unsigned pk2(float a, float b) {
    return bf16_rne(a) | (bf16_rne(b) << 16);
}
__device__ __forceinline__ float ubf(unsigned u, int hi) {
    return __uint_as_float(hi ? (u & 0xFFFF0000u) : (u << 16));
}
__device__ __forceinline__ short8 pack_bf16x8(float4 lo, float4 hi) {
    union { unsigned u[4]; short8 s; } r;
    r.u[0] = pk2(lo.x, lo.y); r.u[1] = pk2(lo.z, lo.w);
    r.u[2] = pk2(hi.x, hi.y); r.u[3] = pk2(hi.z, hi.w);
    return r.s;
}

// ---- K0: prep — W1 (fp32 [k][n]) -> bf16 transposed [n][k] ----
__global__ __launch_bounds__(256) void k_prep(
    const float* __restrict__ W1, unsigned short* __restrict__ W1bfT)
{
    int tid = threadIdx.x;
    int s0 = tid * 32;                 // 8192 shorts / 256 threads
    int n  = s0 >> 6;
    #pragma unroll
    for (int i = 0; i < 32; ++i) {
        int s = s0 + i;
        int k = s & 63;
        W1bfT[s] = (unsigned short)bf16_rne(W1[k * HID + n]);
    }
}

// ---- K1: LDS-free MFMA edge-MLP + exp + bucket scatter, plus x->bf16 cast ----
__global__ __launch_bounds__(256) void k_mlpcast(
    const float* __restrict__ ea, const unsigned short* __restrict__ W1bfT,
    const float* __restrict__ b1, const float* __restrict__ W2,
    const float* __restrict__ b2,
    const int* __restrict__ row, const int* __restrict__ col,
    const float* __restrict__ x, unsigned* __restrict__ xb,
    float* __restrict__ dec, float* __restrict__ s_sum,
    int* __restrict__ cursor, int2* __restrict__ bucket)
{
    const int tid = threadIdx.x;

    if (blockIdx.x >= MLPB) {
        // ---- cast path: x fp32 -> packed bf16 (RNE), 2 uint4 per thread ----
        int t = (blockIdx.x - MLPB) * 256 + tid;
        #pragma unroll
        for (int h = 0; h < 2; ++h) {
            int idx = t + h * (CASTB * 256);
            float4 a = ((const float4*)x)[idx * 2];
            float4 b = ((const float4*)x)[idx * 2 + 1];
            uint4 o;
            o.x = pk2(a.x, a.y); o.y = pk2(a.z, a.w);
            o.z = pk2(b.x, b.y); o.w = pk2(b.z, b.w);
            ((uint4*)xb)[idx] = o;
        }
        return;
    }

    // ---- MFMA MLP: 64 edges x 128 hidden, K=64; A & B direct from global ----
    __shared__ float s_w2[HID], s_b1[HID];
    __shared__ float s_logit[64];

    const int eb = blockIdx.x * 64;
    if (tid < HID) { s_w2[tid] = W2[tid]; s_b1[tid] = b1[tid]; }

    const int lane = tid & 63, w = tid >> 6;
    const int i15 = lane & 15, g = lane >> 4;
    const int m = w * 16 + i15;            // edge row within 64-edge tile

    // B fragments (W1^T, identical for all blocks -> L2-broadcast): 64 VGPR
    short8 bfrag[2][8];
    #pragma unroll
    for (int kt = 0; kt < 2; ++kt)
        #pragma unroll
        for (int t = 0; t < 8; ++t)
            bfrag[kt][t] = *(const short8*)&W1bfT[(t * 16 + i15) * 64 + kt * 32 + g * 8];

    // A fragments: per-lane fp32 load + convert (each (edge,k) hits one lane)
    short8 afrag[2];
    #pragma unroll
    for (int kt = 0; kt < 2; ++kt) {
        const float4* src = (const float4*)&ea[(size_t)(eb + m) * D_EDGE + kt * 32 + g * 8];
        afrag[kt] = pack_bf16x8(src[0], src[1]);
    }

    f32x4 acc[8];
    #pragma unroll
    for (int t = 0; t < 8; ++t) acc[t] = (f32x4){0.f, 0.f, 0.f, 0.f};
    #pragma unroll
    for (int kt = 0; kt < 2; ++kt)
        #pragma unroll
        for (int t = 0; t < 8; ++t)
            acc[t] = __builtin_amdgcn_mfma_f32_16x16x32_bf16(afrag[kt], bfrag[kt][t],
                                                             acc[t], 0, 0, 0);
    __syncthreads();   // s_w2/s_b1 ready (overlapped with MFMA)

    // logit[m] = sum_n relu(h[m][n]+b1[n]) * W2[n];  m = w*16 + g*4 + r
    float loc[4] = {0.f, 0.f, 0.f, 0.f};
    #pragma unroll
    for (int t = 0; t < 8; ++t) {
        float w2v = s_w2[t * 16 + i15];
        float bv  = s_b1[t * 16 + i15];
        #pragma unroll
        for (int r = 0; r < 4; ++r)
            loc[r] = fmaf(fmaxf(acc[t][r] + bv, 0.f), w2v, loc[r]);
    }
    #pragma unroll
    for (int r = 0; r < 4; ++r) {
        #pragma unroll
        for (int off = 1; off < 16; off <<= 1)
            loc[r] += __shfl_xor(loc[r], off);
    }
    if (i15 == 0) {
        #pragma unroll
        for (int r = 0; r < 4; ++r)
            s_logit[w * 16 + g * 4 + r] = loc[r];
    }
    __syncthreads();

    if (tid < 64) {
        int e = eb + tid;
        float logit = s_logit[tid] + b2[0];
        dec[e] = logit;
        int r = row[e], c = col[e];
        if (r != c) {
            float ex = expf(logit);          // logits ~ +-3, no max-shift needed
            int seg = 2 * r + ((r < c) ? 0 : 1);
            atomicAdd(&s_sum[seg], ex);
            int pos = atomicAdd(&cursor[seg], 1);
            if (pos < CAP)                   // P(overflow) ~ e^-30
                bucket[((size_t)seg << 6) + pos] = make_int2(c, __float_as_int(ex));
        }
    }
}

// ---- K2: 1 node / 128 threads; combined dir list, 16-deep load pipeline ----
__device__ __forceinline__ void fma8(float4& lo, float4& hi, uint4 v, float w) {
    lo.x = fmaf(w, __uint_as_float(v.x << 16),          lo.x);
    lo.y = fmaf(w, __uint_as_float(v.x & 0xFFFF0000u),  lo.y);
    lo.z = fmaf(w, __uint_as_float(v.y << 16),          lo.z);
    lo.w = fmaf(w, __uint_as_float(v.y & 0xFFFF0000u),  lo.w);
    hi.x = fmaf(w, __uint_as_float(v.z << 16),          hi.x);
    hi.y = fmaf(w, __uint_as_float(v.z & 0xFFFF0000u),  hi.y);
    hi.z = fmaf(w, __uint_as_float(v.w << 16),          hi.z);
    hi.w = fmaf(w, __uint_as_float(v.w & 0xFFFF0000u),  hi.w);
}

__global__ __launch_bounds__(128) void k_gather(
    const uint4* __restrict__ xb,
    const float* __restrict__ s_sum, const int* __restrict__ cursor,
    const int2* __restrict__ bucket,
    const float* __restrict__ Wn, const float* __restrict__ bn,
    float* __restrict__ out)
{
    const int n = blockIdx.x;
    const int t = threadIdx.x;              // 0..127: 16B granule of node

    __shared__ float    sflow[2][NODE_ELEMS];   // fp32 [dir][elem] 8KB
    __shared__ unsigned sxp[512];               // packed bf16 self-x 2KB
    __shared__ float    sW[C_CH * 3 * C_CH];    // 3KB
    __shared__ float    sbn[C_CH];
    __shared__ int2     s_ecw[2 * CAP];         // combined edge list 1KB

    #pragma unroll
    for (int i = 0; i < 6; ++i) sW[i * 128 + t] = Wn[i * 128 + t];
    if (t < C_CH) sbn[t] = bn[t];
    ((uint4*)sxp)[t] = xb[(size_t)n * 128 + t];

    const int c0  = min(cursor[2 * n],     CAP);
    const int c1  = min(cursor[2 * n + 1], CAP);
    const int tot = c0 + c1;
    if (t < c0)        s_ecw[t] = bucket[((size_t)(2 * n)     << 6) + t];
    else if (t < tot)  s_ecw[t] = bucket[((size_t)(2 * n + 1) << 6) + t - c0];
    __syncthreads();

    float4 aLo = make_float4(0,0,0,0), aHi = make_float4(0,0,0,0);  // dir0=out
    float4 bLo = make_float4(0,0,0,0), bHi = make_float4(0,0,0,0);  // dir1=in
    const uint4* xbt = xb + t;

    // i < c0 is wave-uniform (c0 uniform per block): scalar branch, no div.
#define FMAJ(J) { float w = __int_as_float(s_ecw[i + (J)].y);                 \
                  if (i + (J) < c0) fma8(aLo, aHi, v[J], w);                  \
                  else              fma8(bLo, bHi, v[J], w); }

    int i = 0;
    for (; i + 16 <= tot; i += 16) {
        uint4 v[16];
        #pragma unroll
        for (int j = 0; j < 16; ++j) v[j] = xbt[(size_t)s_ecw[i + j].x * 128];
        #pragma unroll
        for (int j = 0; j < 16; ++j) FMAJ(j)
    }
    for (; i + 8 <= tot; i += 8) {
        uint4 v[8];
        #pragma unroll
        for (int j = 0; j < 8; ++j) v[j] = xbt[(size_t)s_ecw[i + j].x * 128];
        #pragma unroll
        for (int j = 0; j < 8; ++j) FMAJ(j)
    }
    for (; i + 4 <= tot; i += 4) {
        uint4 v[4];
        #pragma unroll
        for (int j = 0; j < 4; ++j) v[j] = xbt[(size_t)s_ecw[i + j].x * 128];
        #pragma unroll
        for (int j = 0; j < 4; ++j) FMAJ(j)
    }
    for (; i < tot; ++i) {
        uint4 v[1];
        v[0] = xbt[(size_t)s_ecw[i].x * 128];
        FMAJ(0)
    }
#undef FMAJ

    const float r0 = 1.0f / fmaxf(s_sum[2 * n],     1e-30f);
    const float r1 = 1.0f / fmaxf(s_sum[2 * n + 1], 1e-30f);
    aLo.x *= r0; aLo.y *= r0; aLo.z *= r0; aLo.w *= r0;
    aHi.x *= r0; aHi.y *= r0; aHi.z *= r0; aHi.w *= r0;
    bLo.x *= r1; bLo.y *= r1; bLo.z *= r1; bLo.w *= r1;
    bHi.x *= r1; bHi.y *= r1; bHi.z *= r1; bHi.w *= r1;

    ((float4*)sflow[0])[t * 2]     = aLo;
    ((float4*)sflow[0])[t * 2 + 1] = aHi;
    ((float4*)sflow[1])[t * 2]     = bLo;
    ((float4*)sflow[1])[t * 2 + 1] = bHi;
    __syncthreads();

    // epilogue: 128 threads, each does 8 output channels at one hw
    const int hw = t & 63;
    const int ob = t >> 6;            // 0..1 -> o = ob*8 + k
    const int hv = hw & 1, hq = hw >> 1;
    float vx[C_CH], vi[C_CH], vo[C_CH];
    #pragma unroll
    for (int c = 0; c < C_CH; ++c) {
        vx[c] = ubf(sxp[c * 32 + hq], hv);
        vo[c] = sflow[0][c * HW + hw];
        vi[c] = sflow[1][c * HW + hw];
    }
    float* outb = out + (size_t)n * NODE_ELEMS;
    #pragma unroll
    for (int k = 0; k < 8; ++k) {
        int o = ob * 8 + k;
        float a = sbn[o];
        const float* wr = &sW[o * 3 * C_CH];
        #pragma unroll
        for (int c = 0; c < C_CH; ++c) {
            a = fmaf(vx[c], wr[c],            a);
            a = fmaf(vi[c], wr[C_CH + c],     a);
            a = fmaf(vo[c], wr[2 * C_CH + c], a);
        }
        outb[o * HW + hw] = a;
    }
}

extern "C" void kernel_launch(void* const* d_in, const int* in_sizes, int n_in,
                              void* d_out, int out_size, void* d_ws, size_t ws_size,
                              hipStream_t stream)
{
    const float* x         = (const float*)d_in[0];
    const float* edge_attr = (const float*)d_in[1];
    const float* W1        = (const float*)d_in[2];
    const float* b1        = (const float*)d_in[3];
    const float* W2        = (const float*)d_in[4];
    const float* b2        = (const float*)d_in[5];
    const float* Wn        = (const float*)d_in[6];
    const float* bn        = (const float*)d_in[7];
    const int*   eidx      = (const int*)d_in[8];
    const int*   row       = eidx;
    const int*   col       = eidx + N_EDGES;

    float* out = (float*)d_out;                          // [N,16,8,8]
    float* dec = out + (size_t)N_NODES * NODE_ELEMS;     // [E,1] logits

    // ws layout (4B units):
    // xb16[N*512 uints] | bucket[NSEG*CAP int2] | s_sum[NSEG] | cursor[NSEG] | W1bfT
    unsigned* xb16   = (unsigned*)d_ws;                                   // 20.48 MB
    int2*     bucket = (int2*)(xb16 + (size_t)N_NODES * NODE_ELEMS / 2);  // 10.24 MB
    float*    s_sum  = (float*)(bucket + (size_t)NSEG * CAP);
    int*      cursor = (int*)(s_sum + NSEG);
    unsigned short* W1bfT = (unsigned short*)(cursor + NSEG);             // 16 KB

    hipMemsetAsync(s_sum, 0, 2 * (size_t)NSEG * sizeof(int), stream);

    k_prep<<<1, 256, 0, stream>>>(W1, W1bfT);
    k_mlpcast<<<MLPB + CASTB, 256, 0, stream>>>(edge_attr, W1bfT, b1, W2, b2,
                                                row, col, x, xb16,
                                                dec, s_sum, cursor, bucket);
    k_gather<<<N_NODES, 128, 0, stream>>>((const uint4*)xb16, s_sum, cursor,
                                          bucket, Wn, bn, out);
}

// Round 14
// 93.824 us; speedup vs baseline: 1.5609x; 1.0467x over previous
//
#include <hip/hip_runtime.h>

#define N_NODES 10000
#define N_EDGES 160000
#define D_EDGE  64
#define C_CH    16
#define HW      64            // H*W = 8*8
#define HID     128
#define NODE_ELEMS 1024          // C*H*W floats per node
#define NSEG    (2 * N_NODES)    // (node,dir): dir 0=out(r<c), 1=in(r>c)
#define CAP     64               // bucket capacity per segment
#define MLPB    (N_EDGES / 64)   // 2500 GEMM blocks
#define QUANTB  2500             // quant blocks appended to same grid

typedef __attribute__((ext_vector_type(8))) short short8;   // 8 bf16 (4 VGPR)
typedef __attribute__((ext_vector_type(4))) float f32x4;

__device__ __forceinline__ unsigned bf16_rne(float f) {
    unsigned u = __float_as_uint(f);
    return (u + 0x7FFFu + ((u >> 16) & 1u)) >> 16;
}
__device__ __forceinline__ short8 pack_bf16x8(float4 lo, float4 hi) {
    union { unsigned u[4]; short8 s; } r;
    r.u[0] = bf16_rne(lo.x) | (bf16_rne(lo.y) << 16);
    r.u[1] = bf16_rne(lo.z) | (bf16_rne(lo.w) << 16);
    r.u[2] = bf16_rne(hi.x) | (bf16_rne(hi.y) << 16);
    r.u[3] = bf16_rne(hi.z) | (bf16_rne(hi.w) << 16);
    return r.s;
}

// ---- K0: prep — W1 -> bf16 W1^T, and zero s_sum/cursor (fused memset) ----
__global__ __launch_bounds__(256) void k_prep(
    const float* __restrict__ W1, unsigned short* __restrict__ W1bfT,
    unsigned* __restrict__ zbase)   // s_sum .. cursor = 2*NSEG dwords
{
    int tid = threadIdx.x;
    int s0 = tid * 32;                 // 8192 shorts / 256 threads
    int n  = s0 >> 6;
    #pragma unroll
    for (int i = 0; i < 32; ++i) {
        int s = s0 + i;
        int k = s & 63;
        W1bfT[s] = (unsigned short)bf16_rne(W1[k * HID + n]);
    }
    for (int i = tid; i < 2 * NSEG; i += 256) zbase[i] = 0u;
}

// ---- K1: MFMA edge-MLP + exp + bucket scatter, plus x->int8 quant ----
__device__ __forceinline__ unsigned pb4(float4 f, float inv) {
    int a = (int)rintf(f.x * inv) + 128;
    int b = (int)rintf(f.y * inv) + 128;
    int c = (int)rintf(f.z * inv) + 128;
    int d = (int)rintf(f.w * inv) + 128;
    a = min(255, max(0, a)); b = min(255, max(0, b));
    c = min(255, max(0, c)); d = min(255, max(0, d));
    return (unsigned)a | ((unsigned)b << 8) | ((unsigned)c << 16) | ((unsigned)d << 24);
}
__global__ __launch_bounds__(256) void k_mlpcast(
    const float* __restrict__ ea, const unsigned short* __restrict__ W1bfT,
    const float* __restrict__ b1, const float* __restrict__ W2,
    const float* __restrict__ b2,
    const int* __restrict__ row, const int* __restrict__ col,
    const float* __restrict__ x, unsigned char* __restrict__ xq,
    float* __restrict__ scale,
    float* __restrict__ dec, float* __restrict__ s_sum,
    int* __restrict__ cursor, int2* __restrict__ bucket)
{
    const int tid = threadIdx.x;

    if (blockIdx.x >= MLPB) {
        // ---- quant path: wave per node; per-node scale, int8+128 bytes ----
        const int wv = tid >> 6, ln = tid & 63;
        const int n  = (blockIdx.x - MLPB) * 4 + wv;
        const float4* xs = (const float4*)(x + (size_t)n * NODE_ELEMS) + ln * 4;
        float4 v0 = xs[0], v1 = xs[1], v2 = xs[2], v3 = xs[3];
        float m = fmaxf(fmaxf(fmaxf(fabsf(v0.x), fabsf(v0.y)),
                              fmaxf(fabsf(v0.z), fabsf(v0.w))),
                 fmaxf(fmaxf(fmaxf(fabsf(v1.x), fabsf(v1.y)),
                              fmaxf(fabsf(v1.z), fabsf(v1.w))),
                 fmaxf(fmaxf(fmaxf(fabsf(v2.x), fabsf(v2.y)),
                              fmaxf(fabsf(v2.z), fabsf(v2.w))),
                       fmaxf(fmaxf(fabsf(v3.x), fabsf(v3.y)),
                              fmaxf(fabsf(v3.z), fabsf(v3.w))))));
        #pragma unroll
        for (int off = 1; off < 64; off <<= 1)
            m = fmaxf(m, __shfl_xor(m, off));
        m = fmaxf(m, 1e-20f);
        float inv = 127.0f / m;
        uint4 o;
        o.x = pb4(v0, inv); o.y = pb4(v1, inv);
        o.z = pb4(v2, inv); o.w = pb4(v3, inv);
        ((uint4*)(xq + (size_t)n * NODE_ELEMS))[ln] = o;
        if (ln == 0) scale[n] = m * (1.0f / 127.0f);
        return;
    }

    // ---- MFMA MLP: 64 edges x 128 hidden, K=64; A & B direct from global ----
    __shared__ float s_w2[HID], s_b1[HID];
    __shared__ float s_logit[64];

    const int eb = blockIdx.x * 64;
    if (tid < HID) { s_w2[tid] = W2[tid]; s_b1[tid] = b1[tid]; }

    const int lane = tid & 63, w = tid >> 6;
    const int i15 = lane & 15, g = lane >> 4;
    const int m = w * 16 + i15;            // edge row within 64-edge tile

    short8 bfrag[2][8];
    #pragma unroll
    for (int kt = 0; kt < 2; ++kt)
        #pragma unroll
        for (int t = 0; t < 8; ++t)
            bfrag[kt][t] = *(const short8*)&W1bfT[(t * 16 + i15) * 64 + kt * 32 + g * 8];

    short8 afrag[2];
    #pragma unroll
    for (int kt = 0; kt < 2; ++kt) {
        const float4* src = (const float4*)&ea[(size_t)(eb + m) * D_EDGE + kt * 32 + g * 8];
        afrag[kt] = pack_bf16x8(src[0], src[1]);
    }

    f32x4 acc[8];
    #pragma unroll
    for (int t = 0; t < 8; ++t) acc[t] = (f32x4){0.f, 0.f, 0.f, 0.f};
    #pragma unroll
    for (int kt = 0; kt < 2; ++kt)
        #pragma unroll
        for (int t = 0; t < 8; ++t)
            acc[t] = __builtin_amdgcn_mfma_f32_16x16x32_bf16(afrag[kt], bfrag[kt][t],
                                                             acc[t], 0, 0, 0);
    __syncthreads();   // s_w2/s_b1 ready (overlapped with MFMA)

    float loc[4] = {0.f, 0.f, 0.f, 0.f};
    #pragma unroll
    for (int t = 0; t < 8; ++t) {
        float w2v = s_w2[t * 16 + i15];
        float bv  = s_b1[t * 16 + i15];
        #pragma unroll
        for (int r = 0; r < 4; ++r)
            loc[r] = fmaf(fmaxf(acc[t][r] + bv, 0.f), w2v, loc[r]);
    }
    #pragma unroll
    for (int r = 0; r < 4; ++r) {
        #pragma unroll
        for (int off = 1; off < 16; off <<= 1)
            loc[r] += __shfl_xor(loc[r], off);
    }
    if (i15 == 0) {
        #pragma unroll
        for (int r = 0; r < 4; ++r)
            s_logit[w * 16 + g * 4 + r] = loc[r];
    }
    __syncthreads();

    if (tid < 64) {
        int e = eb + tid;
        float logit = s_logit[tid] + b2[0];
        dec[e] = logit;
        int r = row[e], c = col[e];
        if (r != c) {
            float ex = expf(logit);          // logits ~ +-3, no max-shift needed
            int seg = 2 * r + ((r < c) ? 0 : 1);
            atomicAdd(&s_sum[seg], ex);
            int pos = atomicAdd(&cursor[seg], 1);
            if (pos < CAP)                   // P(overflow) ~ e^-30
                bucket[((size_t)seg << 6) + pos] = make_int2(c, __float_as_int(ex));
        }
    }
}

// ---- K2: int8 gather (1 node / 128 thr) + exact dequant + 1x1 conv ----
__device__ __forceinline__ void acc8(float* A, uint2 v, float ws) {
    A[0] = fmaf(ws, (float)( v.x        & 255u), A[0]);
    A[1] = fmaf(ws, (float)((v.x >>  8) & 255u), A[1]);
    A[2] = fmaf(ws, (float)((v.x >> 16) & 255u), A[2]);
    A[3] = fmaf(ws, (float)( v.x >> 24        ), A[3]);
    A[4] = fmaf(ws, (float)( v.y        & 255u), A[4]);
    A[5] = fmaf(ws, (float)((v.y >>  8) & 255u), A[5]);
    A[6] = fmaf(ws, (float)((v.y >> 16) & 255u), A[6]);
    A[7] = fmaf(ws, (float)( v.y >> 24        ), A[7]);
}

__global__ __launch_bounds__(128) void k_gather(
    const float* __restrict__ x, const unsigned char* __restrict__ xq,
    const float* __restrict__ scale,
    const float* __restrict__ s_sum, const int* __restrict__ cursor,
    const int2* __restrict__ bucket,
    const float* __restrict__ Wn, const float* __restrict__ bn,
    float* __restrict__ out)
{
    const int n = blockIdx.x;
    const int t = threadIdx.x;              // 0..127: 8B granule of node

    __shared__ float sflow[2][NODE_ELEMS];      // fp32 [dir][elem] 8KB
    __shared__ float sW[C_CH * 3 * C_CH];       // 3KB
    __shared__ float sbn[C_CH];
    __shared__ int2  s_ecw[2 * CAP];            // (col, w*scale[col]) 1KB

    #pragma unroll
    for (int i = 0; i < 6; ++i) sW[i * 128 + t] = Wn[i * 128 + t];
    if (t < C_CH) sbn[t] = bn[t];

    const int c0  = min(cursor[2 * n],     CAP);
    const int c1  = min(cursor[2 * n + 1], CAP);
    const int tot = c0 + c1;
    if (t < tot) {
        int2 e = (t < c0) ? bucket[((size_t)(2 * n) << 6) + t]
                          : bucket[((size_t)(2 * n + 1) << 6) + t - c0];
        e.y = __float_as_int(__int_as_float(e.y) * scale[e.x]);   // ws = w*s_col
        s_ecw[t] = e;
    }
    __syncthreads();

    float a[8] = {0,0,0,0,0,0,0,0};   // dir0 = out, raw int accumulation
    float b[8] = {0,0,0,0,0,0,0,0};   // dir1 = in
    float wsA = 0.f, wsB = 0.f;
    const uint2* xqt = (const uint2*)xq + t;   // node stride = 128 uint2

    // i < c0 is wave-uniform (c0 uniform per block): scalar branch, no div.
#define FMAJ(J) { float ws = __int_as_float(s_ecw[i + (J)].y);                \
                  if (i + (J) < c0) { acc8(a, v[J], ws); wsA += ws; }         \
                  else              { acc8(b, v[J], ws); wsB += ws; } }

    int i = 0;
    for (; i + 16 <= tot; i += 16) {
        uint2 v[16];
        #pragma unroll
        for (int j = 0; j < 16; ++j) v[j] = xqt[(size_t)s_ecw[i + j].x * 128];
        #pragma unroll
        for (int j = 0; j < 16; ++j) FMAJ(j)
    }
    for (; i + 8 <= tot; i += 8) {
        uint2 v[8];
        #pragma unroll
        for (int j = 0; j < 8; ++j) v[j] = xqt[(size_t)s_ecw[i + j].x * 128];
        #pragma unroll
        for (int j = 0; j < 8; ++j) FMAJ(j)
    }
    for (; i + 4 <= tot; i += 4) {
        uint2 v[4];
        #pragma unroll
        for (int j = 0; j < 4; ++j) v[j] = xqt[(size_t)s_ecw[i + j].x * 128];
        #pragma unroll
        for (int j = 0; j < 4; ++j) FMAJ(j)
    }
    for (; i < tot; ++i) {
        uint2 v[1];
        v[0] = xqt[(size_t)s_ecw[i].x * 128];
        FMAJ(0)
    }
#undef FMAJ

    // exact dequant: flow = (acc - 128*sum(ws)) / s_sum
    const float r0 = 1.0f / fmaxf(s_sum[2 * n],     1e-30f);
    const float r1 = 1.0f / fmaxf(s_sum[2 * n + 1], 1e-30f);
    const float o0 = 128.0f * wsA, o1 = 128.0f * wsB;
    float4 f;
    f.x = (a[0]-o0)*r0; f.y = (a[1]-o0)*r0; f.z = (a[2]-o0)*r0; f.w = (a[3]-o0)*r0;
    ((float4*)sflow[0])[t * 2] = f;
    f.x = (a[4]-o0)*r0; f.y = (a[5]-o0)*r0; f.z = (a[6]-o0)*r0; f.w = (a[7]-o0)*r0;
    ((float4*)sflow[0])[t * 2 + 1] = f;
    f.x = (b[0]-o1)*r1; f.y = (b[1]-o1)*r1; f.z = (b[2]-o1)*r1; f.w = (b[3]-o1)*r1;
    ((float4*)sflow[1])[t * 2] = f;
    f.x = (b[4]-o1)*r1; f.y = (b[5]-o1)*r1; f.z = (b[6]-o1)*r1; f.w = (b[7]-o1)*r1;
    ((float4*)sflow[1])[t * 2 + 1] = f;
    __syncthreads();

    // epilogue: 128 threads, each does 8 output channels at one hw
    const int hw = t & 63;
    const int ob = t >> 6;            // 0..1 -> o = ob*8 + k
    const float* xb0 = x + (size_t)n * NODE_ELEMS + hw;
    float vx[C_CH], vi[C_CH], vo[C_CH];
    #pragma unroll
    for (int c = 0; c < C_CH; ++c) {
        vx[c] = xb0[c * HW];                 // exact fp32 self-x
        vo[c] = sflow[0][c * HW + hw];
        vi[c] = sflow[1][c * HW + hw];
    }
    float* outb = out + (size_t)n * NODE_ELEMS;
    #pragma unroll
    for (int k = 0; k < 8; ++k) {
        int o = ob * 8 + k;
        float acc = sbn[o];
        const float* wr = &sW[o * 3 * C_CH];
        #pragma unroll
        for (int c = 0; c < C_CH; ++c) {
            acc = fmaf(vx[c], wr[c],            acc);
            acc = fmaf(vi[c], wr[C_CH + c],     acc);
            acc = fmaf(vo[c], wr[2 * C_CH + c], acc);
        }
        outb[o * HW + hw] = acc;
    }
}

extern "C" void kernel_launch(void* const* d_in, const int* in_sizes, int n_in,
                              void* d_out, int out_size, void* d_ws, size_t ws_size,
                              hipStream_t stream)
{
    const float* x         = (const float*)d_in[0];
    const float* edge_attr = (const float*)d_in[1];
    const float* W1        = (const float*)d_in[2];
    const float* b1        = (const float*)d_in[3];
    const float* W2        = (const float*)d_in[4];
    const float* b2        = (const float*)d_in[5];
    const float* Wn        = (const float*)d_in[6];
    const float* bn        = (const float*)d_in[7];
    const int*   eidx      = (const int*)d_in[8];
    const int*   row       = eidx;
    const int*   col       = eidx + N_EDGES;

    float* out = (float*)d_out;                          // [N,16,8,8]
    float* dec = out + (size_t)N_NODES * NODE_ELEMS;     // [E,1] logits

    // ws layout (bytes): xq[N*1024] | scale[N] f32 | bucket[NSEG*CAP int2]
    //                    | s_sum[NSEG] f32 | cursor[NSEG] i32 | W1bfT[8192 u16]
    unsigned char* xq     = (unsigned char*)d_ws;                        // 10.24 MB
    float*         scale  = (float*)(xq + (size_t)N_NODES * NODE_ELEMS); // 40 KB
    int2*          bucket = (int2*)(scale + N_NODES);                    // 10.24 MB
    float*         s_sum  = (float*)(bucket + (size_t)NSEG * CAP);
    int*           cursor = (int*)(s_sum + NSEG);
    unsigned short* W1bfT = (unsigned short*)(cursor + NSEG);            // 16 KB

    k_prep<<<1, 256, 0, stream>>>(W1, W1bfT, (unsigned*)s_sum);
    k_mlpcast<<<MLPB + QUANTB, 256, 0, stream>>>(edge_attr, W1bfT, b1, W2, b2,
                                                 row, col, x, xq, scale,
                                                 dec, s_sum, cursor, bucket);
    k_gather<<<N_NODES, 128, 0, stream>>>(x, xq, scale, s_sum, cursor,
                                          bucket, Wn, bn, out);
}